// Round 3
// baseline (4343.115 us; speedup 1.0000x reference)
//
#include <hip/hip_runtime.h>

typedef __attribute__((ext_vector_type(8))) short s8v;
typedef __attribute__((ext_vector_type(8))) __bf16 bf8v;
typedef __attribute__((ext_vector_type(4))) float f32x4;

#define DEVINL __device__ __forceinline__

DEVINL unsigned short f2bf(float f) {
    unsigned int x = __float_as_uint(f);
    unsigned int r = (x + 0x7FFFu + ((x >> 16) & 1u)) >> 16;
    return (unsigned short)r;
}

DEVINL f32x4 mfma16(s8v a, s8v b, f32x4 c) {
    return __builtin_amdgcn_mfma_f32_16x16x32_bf16(
        __builtin_bit_cast(bf8v, a), __builtin_bit_cast(bf8v, b), c, 0, 0, 0);
}

// ---------------- workspace layout (bytes) ----------------
#define WS_CTR   0                        // [2 layers][2 dirs] counters, 256B apart = 1024
#define WS_HBUF  1024                     // [2 layers][2 dirs][2 buf][32][512] bf16 = 262144
#define WS_ZERO_BYTES 263168
#define WS_WIH   263168                   // bf16 [2][2][1536][1024] = 12582912
#define WS_WHH   (WS_WIH + 12582912)      // bf16 [2][2][1536][512]  = 6291456
#define WS_EMB   (WS_WHH + 6291456)       // bf16 [2048][1024] = 4194304
#define WS_ST1   (WS_EMB + 4194304)       // bf16 [2048][1024] = 4194304
#define WS_GX    (WS_ST1 + 4194304)       // f32  [2048][3072] = 25165824

// ---------------- fp32 -> bf16 convert ----------------
__global__ __launch_bounds__(256) void k_cvt(const float* __restrict__ in,
                                             unsigned short* __restrict__ out, int n) {
    int i0 = (blockIdx.x * 256 + threadIdx.x) * 8;
    if (i0 + 8 > n) return;
    f32x4 a = *(const f32x4*)(in + i0);
    f32x4 b = *(const f32x4*)(in + i0 + 4);
    s8v o;
    o[0] = (short)f2bf(a[0]); o[1] = (short)f2bf(a[1]);
    o[2] = (short)f2bf(a[2]); o[3] = (short)f2bf(a[3]);
    o[4] = (short)f2bf(b[0]); o[5] = (short)f2bf(b[1]);
    o[6] = (short)f2bf(b[2]); o[7] = (short)f2bf(b[3]);
    *(s8v*)(out + i0) = o;
}

// ---------------- conv softmax-attention ----------------
__global__ __launch_bounds__(256) void k_conv(const float* __restrict__ inp,
                                              const float* __restrict__ conv_w,
                                              const float* __restrict__ conv_b,
                                              float* __restrict__ wts_out,
                                              unsigned short* __restrict__ emb) {
    const int bs = blockIdx.x, tid = threadIdx.x;
    __shared__ float xs[32][260];
    __shared__ float sc[4][32];
    __shared__ float wts[4][32];
    const float* x = inp + (size_t)bs * 8192;
    {
        int p = tid >> 3, i0 = (tid & 7) * 32;
        const float* src = x + p * 256 + i0;
        float* dst = &xs[p][i0];
#pragma unroll
        for (int j = 0; j < 32; j += 4) *(f32x4*)(dst + j) = *(const f32x4*)(src + j);
    }
    __syncthreads();
    {
        int p = tid >> 3, o = tid & 7;
        float s0 = 0, s1 = 0, s2 = 0, s3 = 0;
        const float* xp = &xs[p][o * 32];
#pragma unroll
        for (int j = 0; j < 32; j += 4) {
            f32x4 v  = *(const f32x4*)(xp + j);
            f32x4 w0 = *(const f32x4*)(conv_w + o * 32 + j);
            f32x4 w1 = *(const f32x4*)(conv_w + 256 + o * 32 + j);
            f32x4 w2 = *(const f32x4*)(conv_w + 512 + o * 32 + j);
            f32x4 w3 = *(const f32x4*)(conv_w + 768 + o * 32 + j);
#pragma unroll
            for (int q = 0; q < 4; ++q) {
                s0 += v[q] * w0[q]; s1 += v[q] * w1[q];
                s2 += v[q] * w2[q]; s3 += v[q] * w3[q];
            }
        }
#pragma unroll
        for (int d = 4; d; d >>= 1) {
            s0 += __shfl_down(s0, d, 8); s1 += __shfl_down(s1, d, 8);
            s2 += __shfl_down(s2, d, 8); s3 += __shfl_down(s3, d, 8);
        }
        if (o == 0) {
            sc[0][p] = s0 + conv_b[0]; sc[1][p] = s1 + conv_b[1];
            sc[2][p] = s2 + conv_b[2]; sc[3][p] = s3 + conv_b[3];
        }
    }
    __syncthreads();
    if (tid < 4) {
        float mx = -1e30f;
        for (int p = 0; p < 32; ++p) mx = fmaxf(mx, sc[tid][p]);
        float sm = 0.f;
        for (int p = 0; p < 32; ++p) { float e = __expf(sc[tid][p] - mx); wts[tid][p] = e; sm += e; }
        float inv = 1.f / sm;
        for (int p = 0; p < 32; ++p) wts[tid][p] *= inv;
    }
    __syncthreads();
    if (tid < 128) wts_out[(size_t)bs * 128 + tid] = wts[tid >> 5][tid & 31];
    {
        float a0 = 0, a1 = 0, a2 = 0, a3 = 0;
#pragma unroll 8
        for (int p = 0; p < 32; ++p) {
            float v = xs[p][tid];
            a0 += wts[0][p] * v; a1 += wts[1][p] * v;
            a2 += wts[2][p] * v; a3 += wts[3][p] * v;
        }
        unsigned short* e = emb + (size_t)bs * 1024;
        e[tid] = f2bf(a0); e[256 + tid] = f2bf(a1);
        e[512 + tid] = f2bf(a2); e[768 + tid] = f2bf(a3);
    }
}

// ---------------- bf16 GEMM: C[M][N] = A[M][K] * B[N][K]^T + bias[N] ----------------
__global__ __launch_bounds__(256, 2) void k_gemm(const unsigned short* __restrict__ A,
                                                 const unsigned short* __restrict__ B,
                                                 const float* __restrict__ bias,
                                                 float* __restrict__ C,
                                                 int M, int N, int K) {
    const int bm = blockIdx.y * 64, bn = blockIdx.x * 64;
    const int tid = threadIdx.x, w = tid >> 6, l = tid & 63;
    const int wm = (w >> 1) * 32, wn = (w & 1) * 32;
    __shared__ unsigned short As[64][72];
    __shared__ unsigned short Bs[64][72];
    f32x4 acc[2][2] = {};
    const int sr = tid >> 2;
    const int sk = (tid & 3) * 8;
    const int am = (l & 15), ak = (l >> 4) * 8;
    for (int k0 = 0; k0 < K; k0 += 64) {
        s8v a0 = *(const s8v*)(A + (size_t)(bm + sr) * K + k0 + sk);
        s8v a1 = *(const s8v*)(A + (size_t)(bm + sr) * K + k0 + sk + 32);
        s8v b0 = *(const s8v*)(B + (size_t)(bn + sr) * K + k0 + sk);
        s8v b1 = *(const s8v*)(B + (size_t)(bn + sr) * K + k0 + sk + 32);
        __syncthreads();
        *(s8v*)&As[sr][sk] = a0; *(s8v*)&As[sr][sk + 32] = a1;
        *(s8v*)&Bs[sr][sk] = b0; *(s8v*)&Bs[sr][sk + 32] = b1;
        __syncthreads();
#pragma unroll
        for (int kk = 0; kk < 64; kk += 32) {
            s8v fa0 = *(const s8v*)&As[wm + am][kk + ak];
            s8v fa1 = *(const s8v*)&As[wm + 16 + am][kk + ak];
            s8v fb0 = *(const s8v*)&Bs[wn + am][kk + ak];
            s8v fb1 = *(const s8v*)&Bs[wn + 16 + am][kk + ak];
            acc[0][0] = mfma16(fa0, fb0, acc[0][0]);
            acc[0][1] = mfma16(fa0, fb1, acc[0][1]);
            acc[1][0] = mfma16(fa1, fb0, acc[1][0]);
            acc[1][1] = mfma16(fa1, fb1, acc[1][1]);
        }
    }
#pragma unroll
    for (int mt = 0; mt < 2; ++mt)
#pragma unroll
        for (int nt = 0; nt < 2; ++nt)
#pragma unroll
            for (int r = 0; r < 4; ++r) {
                int row = bm + wm + mt * 16 + (l >> 4) * 4 + r;
                int col = bn + wn + nt * 16 + (l & 15);
                C[(size_t)row * N + col] = acc[mt][nt][r] + bias[col];
            }
}

// ---------------- GRU scan (one layer, BOTH directions per block) ----------------
// 8 blocks; block jg owns h columns [jg*64, jg*64+64) for BOTH directions.
// 768 threads = 12 waves; wave w owns gh columns w*16..w*16+15 (192 = 3 gates x 64) per dir.
// whh slices for both dirs live in VGPRs (2 x 64 VGPRs/lane). Per step: prefetch gx for
// both dirs -> FWD phase -> BWD phase; each phase: single-thread poll -> direct
// global->VGPR A-fragments -> MFMA -> gates -> write-through publish -> drain ->
// release add -> states stores (off the signaling path). Interleaving the two
// independent recurrences hides each one's broadcast latency under the other's compute.
#define PHASE(DIR, S, BFRAG, PR, PZ, PN, HP)                                            \
  {                                                                                     \
    unsigned int* ctr = ctrs + (DIR) * 64;                                              \
    unsigned short* hb = hbuf + (size_t)(DIR) * 32768;                                  \
    const float* BH = bhh + (DIR) * 1536;                                               \
    if (t > 0 && tid == 0) {                                                            \
      while (__hip_atomic_load(ctr, __ATOMIC_RELAXED, __HIP_MEMORY_SCOPE_AGENT) <       \
             (unsigned)(8 * t))                                                         \
        __builtin_amdgcn_s_sleep(1);                                                    \
      (void)__hip_atomic_load(ctr, __ATOMIC_ACQUIRE, __HIP_MEMORY_SCOPE_AGENT);         \
    }                                                                                   \
    __syncthreads();                                                                    \
    {                                                                                   \
      const unsigned short* hc = hb + (size_t)(t & 1) * 16384;                          \
      f32x4 acc0 = {0.f, 0.f, 0.f, 0.f}, acc1 = {0.f, 0.f, 0.f, 0.f};                   \
      const unsigned short* ha = hc + (l & 15) * 512 + (l >> 4) * 8;                    \
      s8v a0[16], a1[16];                                                               \
      _Pragma("unroll") for (int kt = 0; kt < 16; ++kt) {                               \
        a0[kt] = *(const s8v*)(ha + kt * 32);                                           \
        a1[kt] = *(const s8v*)(ha + 8192 + kt * 32);                                    \
      }                                                                                 \
      _Pragma("unroll") for (int kt = 0; kt < 16; ++kt) {                               \
        acc0 = mfma16(a0[kt], (BFRAG)[kt], acc0);                                       \
        acc1 = mfma16(a1[kt], (BFRAG)[kt], acc1);                                       \
      }                                                                                 \
      _Pragma("unroll") for (int r = 0; r < 4; ++r) {                                   \
        gh[(l >> 4) * 4 + r][cl] = acc0[r];                                             \
        gh[16 + (l >> 4) * 4 + r][cl] = acc1[r];                                        \
      }                                                                                 \
    }                                                                                   \
    __syncthreads();                                                                    \
    unsigned int* hnw = (unsigned int*)(hb + (size_t)((t + 1) & 1) * 16384);            \
    float sh0[2], sh1[2];                                                               \
    _Pragma("unroll") for (int nt = 0; nt < 2; ++nt) {                                  \
      if (nt == 0 || has2) {                                                            \
        const int task = nt ? 768 + tid : tid;                                          \
        const int b = task >> 5, jj = (task & 31) * 2, j = jb + jj;                     \
        float hr0 = gh[b][jj] + BH[j];                                                  \
        float hr1 = gh[b][jj + 1] + BH[j + 1];                                          \
        float hz0 = gh[b][64 + jj] + BH[512 + j];                                       \
        float hz1 = gh[b][64 + jj + 1] + BH[512 + j + 1];                               \
        float hn0 = gh[b][128 + jj] + BH[1024 + j];                                     \
        float hn1 = gh[b][128 + jj + 1] + BH[1024 + j + 1];                             \
        float r0 = __builtin_amdgcn_rcpf(1.f + __expf(-((PR)[nt].x + hr0)));            \
        float r1 = __builtin_amdgcn_rcpf(1.f + __expf(-((PR)[nt].y + hr1)));            \
        float z0 = __builtin_amdgcn_rcpf(1.f + __expf(-((PZ)[nt].x + hz0)));            \
        float z1 = __builtin_amdgcn_rcpf(1.f + __expf(-((PZ)[nt].y + hz1)));            \
        float q0 = fminf(fmaxf((PN)[nt].x + r0 * hn0, -15.f), 15.f);                    \
        float q1 = fminf(fmaxf((PN)[nt].y + r1 * hn1, -15.f), 15.f);                    \
        float e0 = __expf(2.f * q0), e1 = __expf(2.f * q1);                             \
        float n0 = (e0 - 1.f) * __builtin_amdgcn_rcpf(e0 + 1.f);                        \
        float n1 = (e1 - 1.f) * __builtin_amdgcn_rcpf(e1 + 1.f);                        \
        float h0 = (1.f - z0) * n0 + z0 * (HP)[nt][0];                                  \
        float h1 = (1.f - z1) * n1 + z1 * (HP)[nt][1];                                  \
        (HP)[nt][0] = h0; (HP)[nt][1] = h1;                                             \
        sh0[nt] = h0; sh1[nt] = h1;                                                     \
        unsigned int packed = (unsigned int)f2bf(h0) | ((unsigned int)f2bf(h1) << 16);  \
        __hip_atomic_store(&hnw[b * 256 + (j >> 1)], packed, __ATOMIC_RELAXED,          \
                           __HIP_MEMORY_SCOPE_AGENT);                                   \
      }                                                                                 \
    }                                                                                   \
    __syncthreads();                                                                    \
    if (tid == 0 && t < 63)                                                             \
      (void)__hip_atomic_fetch_add(ctr, 1u, __ATOMIC_RELEASE, __HIP_MEMORY_SCOPE_AGENT);\
    _Pragma("unroll") for (int nt = 0; nt < 2; ++nt) {                                  \
      if (nt == 0 || has2) {                                                            \
        const int task = nt ? 768 + tid : tid;                                          \
        const int b = task >> 5, jj = (task & 31) * 2, j = jb + jj;                     \
        const size_t so = (size_t)(b * 64 + (S)) * 1024 + (DIR) * 512 + j;              \
        if (st32) *(float2*)(st32 + so) = make_float2(sh0[nt], sh1[nt]);                \
        if (st16) ((unsigned int*)st16)[so >> 1] =                                      \
            (unsigned int)f2bf(sh0[nt]) | ((unsigned int)f2bf(sh1[nt]) << 16);          \
      }                                                                                 \
    }                                                                                   \
  }

__global__ __launch_bounds__(768, 1) void k_scan(const float* __restrict__ gx,   // [2048][3072]
                                                 const unsigned short* __restrict__ whh, // [2][1536][512]
                                                 const float* __restrict__ bhh,  // [2][1536]
                                                 unsigned short* __restrict__ hbuf, // [2 dir][2 buf][32][512]
                                                 unsigned int* __restrict__ ctrs,  // [2 dir] 64-uint stride
                                                 float* __restrict__ st32,
                                                 unsigned short* __restrict__ st16) {
    const int jg = blockIdx.x;           // 0..7: column slice (both dirs)
    const int tid = threadIdx.x;
    const int w = tid >> 6, l = tid & 63;
    __shared__ float gh[32][196];

    // persistent B fragments, both directions
    const int cl = w * 16 + (l & 15);                  // 0..191
    const int R = (cl >> 6) * 512 + jg * 64 + (cl & 63);
    s8v bfragF[16], bfragB[16];
    {
        const unsigned short* wrF = whh + (size_t)R * 512 + (l >> 4) * 8;
        const unsigned short* wrB = wrF + (size_t)1536 * 512;
#pragma unroll
        for (int kt = 0; kt < 16; ++kt) {
            bfragF[kt] = *(const s8v*)(wrF + kt * 32);
            bfragB[kt] = *(const s8v*)(wrB + kt * 32);
        }
    }
    const int jb = jg * 64;
    const int has2 = (tid < 256);
    float hpF[2][2] = {{0.f, 0.f}, {0.f, 0.f}};
    float hpB[2][2] = {{0.f, 0.f}, {0.f, 0.f}};

    for (int t = 0; t < 64; ++t) {
        const int sF = t, sB = 63 - t;
        // ---- prefetch gx for both dirs / both task rounds (hides HBM latency) ----
        float2 prF[2], pzF[2], pnF[2], prB[2], pzB[2], pnB[2];
        {
            const int b0 = tid >> 5, jp0 = (tid & 31) * 2;
            const float* gF = gx + (size_t)(b0 * 64 + sF) * 3072 + jb + jp0;
            const float* gB = gx + (size_t)(b0 * 64 + sB) * 3072 + 1536 + jb + jp0;
            prF[0] = *(const float2*)(gF);
            pzF[0] = *(const float2*)(gF + 512);
            pnF[0] = *(const float2*)(gF + 1024);
            prB[0] = *(const float2*)(gB);
            pzB[0] = *(const float2*)(gB + 512);
            pnB[0] = *(const float2*)(gB + 1024);
            if (has2) {
                const int tk = 768 + tid, b1 = tk >> 5, jp1 = (tk & 31) * 2;
                const float* gF1 = gx + (size_t)(b1 * 64 + sF) * 3072 + jb + jp1;
                const float* gB1 = gx + (size_t)(b1 * 64 + sB) * 3072 + 1536 + jb + jp1;
                prF[1] = *(const float2*)(gF1);
                pzF[1] = *(const float2*)(gF1 + 512);
                pnF[1] = *(const float2*)(gF1 + 1024);
                prB[1] = *(const float2*)(gB1);
                pzB[1] = *(const float2*)(gB1 + 512);
                pnB[1] = *(const float2*)(gB1 + 1024);
            }
        }
        PHASE(0, sF, bfragF, prF, pzF, pnF, hpF)
        PHASE(1, sB, bfragB, prB, pzB, pnB, hpB)
    }
}

// ---------------- finale ----------------
__global__ __launch_bounds__(256) void k_finale(const float* __restrict__ states,
                                                const float* __restrict__ conv2_w,
                                                const float* __restrict__ conv2_b,
                                                const float* __restrict__ demoip,
                                                const float* __restrict__ lin_w,
                                                const float* __restrict__ lin_b,
                                                float* __restrict__ out,
                                                float* __restrict__ context,
                                                float* __restrict__ alpha) {
    const int b = blockIdx.x, tid = threadIdx.x, w = tid >> 6, l = tid & 63;
    __shared__ float dots[64], al[64], ctx[1024], lg[2];
    const float* st = states + (size_t)b * 65536;
    for (int si = 0; si < 16; ++si) {
        int s = w * 16 + si;
        const float* row = st + s * 1024;
        float sum = 0.f;
        for (int i = l; i < 1024; i += 64) sum += row[i] * conv2_w[i];
#pragma unroll
        for (int m = 32; m; m >>= 1) sum += __shfl_xor(sum, m, 64);
        if (l == 0) dots[s] = sum + conv2_b[0];
    }
    __syncthreads();
    if (w == 0) {
        float v = dots[l];
        float mx = v;
#pragma unroll
        for (int m = 32; m; m >>= 1) mx = fmaxf(mx, __shfl_xor(mx, m, 64));
        float e = __expf(v - mx);
        float sm = e;
#pragma unroll
        for (int m = 32; m; m >>= 1) sm += __shfl_xor(sm, m, 64);
        float a = e / sm;
        al[l] = a;
        alpha[b * 64 + l] = a;
    }
    __syncthreads();
    for (int h = tid; h < 1024; h += 256) {
        float c = 0.f;
#pragma unroll 8
        for (int s = 0; s < 64; ++s) c += al[s] * st[s * 1024 + h];
        ctx[h] = c;
        context[b * 1024 + h] = c;
    }
    __syncthreads();
    if (w < 2) {
        const float* lw = lin_w + w * 1027;
        float sum = 0.f;
        for (int i = l; i < 1024; i += 64) sum += ctx[i] * lw[i];
#pragma unroll
        for (int m = 32; m; m >>= 1) sum += __shfl_xor(sum, m, 64);
        if (l == 0) {
            sum += lw[1024] * demoip[b * 3] + lw[1025] * demoip[b * 3 + 1] +
                   lw[1026] * demoip[b * 3 + 2] + lin_b[w];
            lg[w] = sum;
        }
    }
    __syncthreads();
    if (tid == 0) {
        float m = fmaxf(lg[0], lg[1]);
        float e0 = __expf(lg[0] - m), e1 = __expf(lg[1] - m);
        float inv = 1.f / (e0 + e1);
        out[b * 2 + 0] = e0 * inv;
        out[b * 2 + 1] = e1 * inv;
    }
}

extern "C" void kernel_launch(void* const* d_in, const int* in_sizes, int n_in,
                              void* d_out, int out_size, void* d_ws, size_t ws_size,
                              hipStream_t stream) {
    const float* inputs  = (const float*)d_in[0];
    const float* demoip  = (const float*)d_in[1];
    const float* conv_w  = (const float*)d_in[2];
    const float* conv_b  = (const float*)d_in[3];
    const float* conv2_w = (const float*)d_in[4];
    const float* conv2_b = (const float*)d_in[5];
    const float* wih     = (const float*)d_in[6];
    const float* whh     = (const float*)d_in[7];
    const float* bih     = (const float*)d_in[8];
    const float* bhh     = (const float*)d_in[9];
    const float* lin_w   = (const float*)d_in[10];
    const float* lin_b   = (const float*)d_in[11];

    char* ws = (char*)d_ws;
    unsigned int* ctrs    = (unsigned int*)(ws + WS_CTR);
    unsigned short* hbuf  = (unsigned short*)(ws + WS_HBUF);
    unsigned short* wih16 = (unsigned short*)(ws + WS_WIH);
    unsigned short* whh16 = (unsigned short*)(ws + WS_WHH);
    unsigned short* emb16 = (unsigned short*)(ws + WS_EMB);
    unsigned short* st116 = (unsigned short*)(ws + WS_ST1);
    float* gxbuf          = (float*)(ws + WS_GX);

    float* out_out    = (float*)d_out;
    float* wts_out    = out_out + 64;
    float* states_out = out_out + 262208;
    float* ctx_out    = out_out + 2359360;
    float* alpha_out  = out_out + 2392128;

    hipMemsetAsync(ws, 0, WS_ZERO_BYTES, stream);
    k_cvt<<<3072, 256, 0, stream>>>(wih, wih16, 6291456);
    k_cvt<<<1536, 256, 0, stream>>>(whh, whh16, 3145728);
    k_conv<<<2048, 256, 0, stream>>>(inputs, conv_w, conv_b, wts_out, emb16);
    // layer 1
    k_gemm<<<dim3(48, 32), 256, 0, stream>>>(emb16, wih16, bih, gxbuf, 2048, 3072, 1024);
    k_scan<<<8, 768, 0, stream>>>(gxbuf, whh16, bhh, hbuf, ctrs, nullptr, st116);
    // layer 2
    k_gemm<<<dim3(48, 32), 256, 0, stream>>>(st116, wih16 + 3145728, bih + 3072, gxbuf,
                                             2048, 3072, 1024);
    k_scan<<<8, 768, 0, stream>>>(gxbuf, whh16 + 1572864, bhh + 3072, hbuf + 65536,
                                  ctrs + 128, states_out, nullptr);
    k_finale<<<32, 256, 0, stream>>>(states_out, conv2_w, conv2_b, demoip, lin_w, lin_b,
                                     out_out, ctx_out, alpha_out);
}

// Round 4
// 880.803 us; speedup vs baseline: 4.9309x; 4.9309x over previous
//
#include <hip/hip_runtime.h>

typedef __attribute__((ext_vector_type(8))) short s8v;
typedef __attribute__((ext_vector_type(8))) __bf16 bf8v;
typedef __attribute__((ext_vector_type(4))) float f32x4;

#define DEVINL __device__ __forceinline__

DEVINL unsigned short f2bf(float f) {
    unsigned int x = __float_as_uint(f);
    unsigned int r = (x + 0x7FFFu + ((x >> 16) & 1u)) >> 16;
    return (unsigned short)r;
}

DEVINL f32x4 mfma16(s8v a, s8v b, f32x4 c) {
    return __builtin_amdgcn_mfma_f32_16x16x32_bf16(
        __builtin_bit_cast(bf8v, a), __builtin_bit_cast(bf8v, b), c, 0, 0, 0);
}

// ---------------- workspace layout (bytes) ----------------
#define WS_CTR   0                        // [2 layers][2 dirs][8 producers] seq words, 64B apart
#define WS_HBUF  4096                     // [2 layers][2 dirs][2 buf][32][512] bf16 = 262144
#define WS_ZERO_BYTES 266240
#define WS_WIH   266240                   // bf16 [2][2][1536][1024] = 12582912
#define WS_WHH   (WS_WIH + 12582912)      // bf16 [2][2][1536][512]  = 6291456
#define WS_EMB   (WS_WHH + 6291456)       // bf16 [2048][1024] = 4194304
#define WS_ST1   (WS_EMB + 4194304)       // bf16 [2048][1024] = 4194304
#define WS_GX    (WS_ST1 + 4194304)       // f32  [2048][3072] = 25165824

// ---------------- fp32 -> bf16 convert ----------------
__global__ __launch_bounds__(256) void k_cvt(const float* __restrict__ in,
                                             unsigned short* __restrict__ out, int n) {
    int i0 = (blockIdx.x * 256 + threadIdx.x) * 8;
    if (i0 + 8 > n) return;
    f32x4 a = *(const f32x4*)(in + i0);
    f32x4 b = *(const f32x4*)(in + i0 + 4);
    s8v o;
    o[0] = (short)f2bf(a[0]); o[1] = (short)f2bf(a[1]);
    o[2] = (short)f2bf(a[2]); o[3] = (short)f2bf(a[3]);
    o[4] = (short)f2bf(b[0]); o[5] = (short)f2bf(b[1]);
    o[6] = (short)f2bf(b[2]); o[7] = (short)f2bf(b[3]);
    *(s8v*)(out + i0) = o;
}

// ---------------- conv softmax-attention ----------------
__global__ __launch_bounds__(256) void k_conv(const float* __restrict__ inp,
                                              const float* __restrict__ conv_w,
                                              const float* __restrict__ conv_b,
                                              float* __restrict__ wts_out,
                                              unsigned short* __restrict__ emb) {
    const int bs = blockIdx.x, tid = threadIdx.x;
    __shared__ float xs[32][260];
    __shared__ float sc[4][32];
    __shared__ float wts[4][32];
    const float* x = inp + (size_t)bs * 8192;
    {
        int p = tid >> 3, i0 = (tid & 7) * 32;
        const float* src = x + p * 256 + i0;
        float* dst = &xs[p][i0];
#pragma unroll
        for (int j = 0; j < 32; j += 4) *(f32x4*)(dst + j) = *(const f32x4*)(src + j);
    }
    __syncthreads();
    {
        int p = tid >> 3, o = tid & 7;
        float s0 = 0, s1 = 0, s2 = 0, s3 = 0;
        const float* xp = &xs[p][o * 32];
#pragma unroll
        for (int j = 0; j < 32; j += 4) {
            f32x4 v  = *(const f32x4*)(xp + j);
            f32x4 w0 = *(const f32x4*)(conv_w + o * 32 + j);
            f32x4 w1 = *(const f32x4*)(conv_w + 256 + o * 32 + j);
            f32x4 w2 = *(const f32x4*)(conv_w + 512 + o * 32 + j);
            f32x4 w3 = *(const f32x4*)(conv_w + 768 + o * 32 + j);
#pragma unroll
            for (int q = 0; q < 4; ++q) {
                s0 += v[q] * w0[q]; s1 += v[q] * w1[q];
                s2 += v[q] * w2[q]; s3 += v[q] * w3[q];
            }
        }
#pragma unroll
        for (int d = 4; d; d >>= 1) {
            s0 += __shfl_down(s0, d, 8); s1 += __shfl_down(s1, d, 8);
            s2 += __shfl_down(s2, d, 8); s3 += __shfl_down(s3, d, 8);
        }
        if (o == 0) {
            sc[0][p] = s0 + conv_b[0]; sc[1][p] = s1 + conv_b[1];
            sc[2][p] = s2 + conv_b[2]; sc[3][p] = s3 + conv_b[3];
        }
    }
    __syncthreads();
    if (tid < 4) {
        float mx = -1e30f;
        for (int p = 0; p < 32; ++p) mx = fmaxf(mx, sc[tid][p]);
        float sm = 0.f;
        for (int p = 0; p < 32; ++p) { float e = __expf(sc[tid][p] - mx); wts[tid][p] = e; sm += e; }
        float inv = 1.f / sm;
        for (int p = 0; p < 32; ++p) wts[tid][p] *= inv;
    }
    __syncthreads();
    if (tid < 128) wts_out[(size_t)bs * 128 + tid] = wts[tid >> 5][tid & 31];
    {
        float a0 = 0, a1 = 0, a2 = 0, a3 = 0;
#pragma unroll 8
        for (int p = 0; p < 32; ++p) {
            float v = xs[p][tid];
            a0 += wts[0][p] * v; a1 += wts[1][p] * v;
            a2 += wts[2][p] * v; a3 += wts[3][p] * v;
        }
        unsigned short* e = emb + (size_t)bs * 1024;
        e[tid] = f2bf(a0); e[256 + tid] = f2bf(a1);
        e[512 + tid] = f2bf(a2); e[768 + tid] = f2bf(a3);
    }
}

// ---------------- bf16 GEMM: C[M][N] = A[M][K] * B[N][K]^T + bias[N] ----------------
__global__ __launch_bounds__(256, 2) void k_gemm(const unsigned short* __restrict__ A,
                                                 const unsigned short* __restrict__ B,
                                                 const float* __restrict__ bias,
                                                 float* __restrict__ C,
                                                 int M, int N, int K) {
    const int bm = blockIdx.y * 64, bn = blockIdx.x * 64;
    const int tid = threadIdx.x, w = tid >> 6, l = tid & 63;
    const int wm = (w >> 1) * 32, wn = (w & 1) * 32;
    __shared__ unsigned short As[64][72];
    __shared__ unsigned short Bs[64][72];
    f32x4 acc[2][2] = {};
    const int sr = tid >> 2;
    const int sk = (tid & 3) * 8;
    const int am = (l & 15), ak = (l >> 4) * 8;
    for (int k0 = 0; k0 < K; k0 += 64) {
        s8v a0 = *(const s8v*)(A + (size_t)(bm + sr) * K + k0 + sk);
        s8v a1 = *(const s8v*)(A + (size_t)(bm + sr) * K + k0 + sk + 32);
        s8v b0 = *(const s8v*)(B + (size_t)(bn + sr) * K + k0 + sk);
        s8v b1 = *(const s8v*)(B + (size_t)(bn + sr) * K + k0 + sk + 32);
        __syncthreads();
        *(s8v*)&As[sr][sk] = a0; *(s8v*)&As[sr][sk + 32] = a1;
        *(s8v*)&Bs[sr][sk] = b0; *(s8v*)&Bs[sr][sk + 32] = b1;
        __syncthreads();
#pragma unroll
        for (int kk = 0; kk < 64; kk += 32) {
            s8v fa0 = *(const s8v*)&As[wm + am][kk + ak];
            s8v fa1 = *(const s8v*)&As[wm + 16 + am][kk + ak];
            s8v fb0 = *(const s8v*)&Bs[wn + am][kk + ak];
            s8v fb1 = *(const s8v*)&Bs[wn + 16 + am][kk + ak];
            acc[0][0] = mfma16(fa0, fb0, acc[0][0]);
            acc[0][1] = mfma16(fa0, fb1, acc[0][1]);
            acc[1][0] = mfma16(fa1, fb0, acc[1][0]);
            acc[1][1] = mfma16(fa1, fb1, acc[1][1]);
        }
    }
#pragma unroll
    for (int mt = 0; mt < 2; ++mt)
#pragma unroll
        for (int nt = 0; nt < 2; ++nt)
#pragma unroll
            for (int r = 0; r < 4; ++r) {
                int row = bm + wm + mt * 16 + (l >> 4) * 4 + r;
                int col = bn + wn + nt * 16 + (l & 15);
                C[(size_t)row * N + col] = acc[mt][nt][r] + bias[col];
            }
}

// ---------------- GRU scan (one layer, both directions, round-2 topology) ----------------
// 16 blocks of 256 thr: dir = blk>>3, jg = blk&7 owns h cols [jg*64, jg*64+64).
// 4 waves; wave w owns cols jb + w*16 + (l&15), with ALL THREE gate B-tiles in VGPRs
// (192 regs) so r/z/n for the same (col,batch) land in the same lane -> gates fully in
// registers (no gh LDS, no hprev LDS, one less barrier). Per step:
//   prefetch gx (24 dwords) -> poll 8 per-producer seq words (wave 0, lanes 0-7) ->
//   acquire -> stage h into LDS (XOR-swizzled) -> sync -> MFMA (32 ds_read, 96 mfma) ->
//   gates in regs -> publish h' (2B write-through stores) -> sync (vmcnt drain) ->
//   release seq-word store -> states stores (off the signaling path).
__global__ __launch_bounds__(256, 1) void k_scan(const float* __restrict__ gx,   // [2048][3072]
                                                 const unsigned short* __restrict__ whh, // [2][1536][512]
                                                 const float* __restrict__ bhh,  // [2][1536]
                                                 unsigned short* __restrict__ hbuf, // [2 dir][2 buf][32][512]
                                                 unsigned int* __restrict__ flags,  // [2 dir][8] 64B apart
                                                 float* __restrict__ st32,
                                                 unsigned short* __restrict__ st16) {
    const int blk = blockIdx.x;
    const int dir = blk >> 3, jg = blk & 7;
    const int tid = threadIdx.x;
    const int w = tid >> 6, l = tid & 63;
    const int lr = l & 15, lq = l >> 4;
    const int jb = jg * 64;
    const int mycol = jb + w * 16 + lr;

    __shared__ __align__(1024) unsigned short hs[16384]; // [32][512] bf16, XOR-swizzled

    // persistent B fragments: 3 gates x 16 k-tiles (192 VGPRs)
    s8v bf[3][16];
#pragma unroll
    for (int g = 0; g < 3; ++g) {
        const unsigned short* wr =
            whh + ((size_t)dir * 1536 + g * 512 + mycol) * 512 + lq * 8;
#pragma unroll
        for (int kt = 0; kt < 16; ++kt) bf[g][kt] = *(const s8v*)(wr + kt * 32);
    }
    float bh_[3];
#pragma unroll
    for (int g = 0; g < 3; ++g) bh_[g] = bhh[dir * 1536 + g * 512 + mycol];

    unsigned short* hb0 = hbuf + (size_t)dir * 32768;
    unsigned int* fl = flags + dir * 128;          // 8 producers, 16-uint stride
    unsigned int* myflag = fl + jg * 16;

    float hp[2][4] = {{0.f, 0.f, 0.f, 0.f}, {0.f, 0.f, 0.f, 0.f}};

    for (int t = 0; t < 64; ++t) {
        const int s = dir ? (63 - t) : t;
        // ---- prefetch gx: [gate][batch-tile][row] (independent of h; issued pre-poll) ----
        float pg[3][2][4];
#pragma unroll
        for (int g = 0; g < 3; ++g)
#pragma unroll
            for (int bt = 0; bt < 2; ++bt)
#pragma unroll
                for (int r = 0; r < 4; ++r) {
                    const int b = bt * 16 + lq * 4 + r;
                    pg[g][bt][r] = gx[(size_t)(b * 64 + s) * 3072 + dir * 1536 +
                                      g * 512 + mycol];
                }
        // ---- wait for all 8 producers of this direction to publish h_t ----
        if (t > 0) {
            if (w == 0 && l < 8) {
                while (__hip_atomic_load(&fl[l * 16], __ATOMIC_RELAXED,
                                         __HIP_MEMORY_SCOPE_AGENT) < (unsigned)t)
                    __builtin_amdgcn_s_sleep(1);
            }
            if (tid == 0)
                (void)__hip_atomic_load(&fl[0], __ATOMIC_ACQUIRE,
                                        __HIP_MEMORY_SCOPE_AGENT);
            __syncthreads();
        }
        // ---- stage h_t into LDS (swizzled) ----
        const unsigned short* hc = hb0 + (size_t)(t & 1) * 16384;
#pragma unroll
        for (int i = 0; i < 8; ++i) {
            const int c = tid + 256 * i;
            const int row = c >> 6, inb = (c & 63) * 16;
            *(s8v*)((char*)hs + row * 1024 + (inb ^ ((row & 7) << 4))) =
                *(const s8v*)(hc + c * 8);
        }
        __syncthreads();
        // ---- MFMA: 3 gate-tiles x 2 batch-tiles, A-frag shared across gates ----
        f32x4 acc[3][2] = {};
#pragma unroll
        for (int bt = 0; bt < 2; ++bt) {
            const int row = bt * 16 + lr;
            const int m = (row & 7) << 4;
#pragma unroll
            for (int kt = 0; kt < 16; ++kt) {
                s8v a = *(const s8v*)((const char*)hs + row * 1024 +
                                      ((kt * 64 + lq * 16) ^ m));
                acc[0][bt] = mfma16(a, bf[0][kt], acc[0][bt]);
                acc[1][bt] = mfma16(a, bf[1][kt], acc[1][bt]);
                acc[2][bt] = mfma16(a, bf[2][kt], acc[2][bt]);
            }
        }
        // ---- gates fully in registers + publish h_{t+1} ----
        unsigned short* hnw = hb0 + (size_t)((t + 1) & 1) * 16384;
        float hnew[2][4];
#pragma unroll
        for (int bt = 0; bt < 2; ++bt)
#pragma unroll
            for (int r = 0; r < 4; ++r) {
                const int b = bt * 16 + lq * 4 + r;
                float r_ = __builtin_amdgcn_rcpf(
                    1.f + __expf(-(pg[0][bt][r] + acc[0][bt][r] + bh_[0])));
                float z_ = __builtin_amdgcn_rcpf(
                    1.f + __expf(-(pg[1][bt][r] + acc[1][bt][r] + bh_[1])));
                float q = pg[2][bt][r] + r_ * (acc[2][bt][r] + bh_[2]);
                q = fminf(fmaxf(q, -15.f), 15.f);
                float e = __expf(2.f * q);
                float n_ = (e - 1.f) * __builtin_amdgcn_rcpf(e + 1.f);
                float h = (1.f - z_) * n_ + z_ * hp[bt][r];
                hp[bt][r] = h;
                hnew[bt][r] = h;
                __hip_atomic_store(&hnw[b * 512 + mycol], f2bf(h), __ATOMIC_RELAXED,
                                   __HIP_MEMORY_SCOPE_AGENT);
            }
        __syncthreads();  // vmcnt(0) drain for every wave -> publishes globally visible
        if (tid == 0 && t < 63)
            __hip_atomic_store(myflag, (unsigned)(t + 1), __ATOMIC_RELEASE,
                               __HIP_MEMORY_SCOPE_AGENT);
        // ---- states stores, off the signaling path ----
#pragma unroll
        for (int bt = 0; bt < 2; ++bt)
#pragma unroll
            for (int r = 0; r < 4; ++r) {
                const int b = bt * 16 + lq * 4 + r;
                const size_t so = (size_t)(b * 64 + s) * 1024 + dir * 512 + mycol;
                if (st32) st32[so] = hnew[bt][r];
                if (st16) st16[so] = f2bf(hnew[bt][r]);
            }
    }
}

// ---------------- finale ----------------
__global__ __launch_bounds__(256) void k_finale(const float* __restrict__ states,
                                                const float* __restrict__ conv2_w,
                                                const float* __restrict__ conv2_b,
                                                const float* __restrict__ demoip,
                                                const float* __restrict__ lin_w,
                                                const float* __restrict__ lin_b,
                                                float* __restrict__ out,
                                                float* __restrict__ context,
                                                float* __restrict__ alpha) {
    const int b = blockIdx.x, tid = threadIdx.x, w = tid >> 6, l = tid & 63;
    __shared__ float dots[64], al[64], ctx[1024], lg[2];
    const float* st = states + (size_t)b * 65536;
    for (int si = 0; si < 16; ++si) {
        int s = w * 16 + si;
        const float* row = st + s * 1024;
        float sum = 0.f;
        for (int i = l; i < 1024; i += 64) sum += row[i] * conv2_w[i];
#pragma unroll
        for (int m = 32; m; m >>= 1) sum += __shfl_xor(sum, m, 64);
        if (l == 0) dots[s] = sum + conv2_b[0];
    }
    __syncthreads();
    if (w == 0) {
        float v = dots[l];
        float mx = v;
#pragma unroll
        for (int m = 32; m; m >>= 1) mx = fmaxf(mx, __shfl_xor(mx, m, 64));
        float e = __expf(v - mx);
        float sm = e;
#pragma unroll
        for (int m = 32; m; m >>= 1) sm += __shfl_xor(sm, m, 64);
        float a = e / sm;
        al[l] = a;
        alpha[b * 64 + l] = a;
    }
    __syncthreads();
    for (int h = tid; h < 1024; h += 256) {
        float c = 0.f;
#pragma unroll 8
        for (int s = 0; s < 64; ++s) c += al[s] * st[s * 1024 + h];
        ctx[h] = c;
        context[b * 1024 + h] = c;
    }
    __syncthreads();
    if (w < 2) {
        const float* lw = lin_w + w * 1027;
        float sum = 0.f;
        for (int i = l; i < 1024; i += 64) sum += ctx[i] * lw[i];
#pragma unroll
        for (int m = 32; m; m >>= 1) sum += __shfl_xor(sum, m, 64);
        if (l == 0) {
            sum += lw[1024] * demoip[b * 3] + lw[1025] * demoip[b * 3 + 1] +
                   lw[1026] * demoip[b * 3 + 2] + lin_b[w];
            lg[w] = sum;
        }
    }
    __syncthreads();
    if (tid == 0) {
        float m = fmaxf(lg[0], lg[1]);
        float e0 = __expf(lg[0] - m), e1 = __expf(lg[1] - m);
        float inv = 1.f / (e0 + e1);
        out[b * 2 + 0] = e0 * inv;
        out[b * 2 + 1] = e1 * inv;
    }
}

extern "C" void kernel_launch(void* const* d_in, const int* in_sizes, int n_in,
                              void* d_out, int out_size, void* d_ws, size_t ws_size,
                              hipStream_t stream) {
    const float* inputs  = (const float*)d_in[0];
    const float* demoip  = (const float*)d_in[1];
    const float* conv_w  = (const float*)d_in[2];
    const float* conv_b  = (const float*)d_in[3];
    const float* conv2_w = (const float*)d_in[4];
    const float* conv2_b = (const float*)d_in[5];
    const float* wih     = (const float*)d_in[6];
    const float* whh     = (const float*)d_in[7];
    const float* bih     = (const float*)d_in[8];
    const float* bhh     = (const float*)d_in[9];
    const float* lin_w   = (const float*)d_in[10];
    const float* lin_b   = (const float*)d_in[11];

    char* ws = (char*)d_ws;
    unsigned int* ctrs    = (unsigned int*)(ws + WS_CTR);
    unsigned short* hbuf  = (unsigned short*)(ws + WS_HBUF);
    unsigned short* wih16 = (unsigned short*)(ws + WS_WIH);
    unsigned short* whh16 = (unsigned short*)(ws + WS_WHH);
    unsigned short* emb16 = (unsigned short*)(ws + WS_EMB);
    unsigned short* st116 = (unsigned short*)(ws + WS_ST1);
    float* gxbuf          = (float*)(ws + WS_GX);

    float* out_out    = (float*)d_out;
    float* wts_out    = out_out + 64;
    float* states_out = out_out + 262208;
    float* ctx_out    = out_out + 2359360;
    float* alpha_out  = out_out + 2392128;

    hipMemsetAsync(ws, 0, WS_ZERO_BYTES, stream);
    k_cvt<<<3072, 256, 0, stream>>>(wih, wih16, 6291456);
    k_cvt<<<1536, 256, 0, stream>>>(whh, whh16, 3145728);
    k_conv<<<2048, 256, 0, stream>>>(inputs, conv_w, conv_b, wts_out, emb16);
    // layer 1
    k_gemm<<<dim3(48, 32), 256, 0, stream>>>(emb16, wih16, bih, gxbuf, 2048, 3072, 1024);
    k_scan<<<16, 256, 0, stream>>>(gxbuf, whh16, bhh, hbuf, ctrs, nullptr, st116);
    // layer 2
    k_gemm<<<dim3(48, 32), 256, 0, stream>>>(st116, wih16 + 3145728, bih + 3072, gxbuf,
                                             2048, 3072, 1024);
    k_scan<<<16, 256, 0, stream>>>(gxbuf, whh16 + 1572864, bhh + 3072, hbuf + 65536,
                                   ctrs + 256, states_out, nullptr);
    k_finale<<<32, 256, 0, stream>>>(states_out, conv2_w, conv2_b, demoip, lin_w, lin_b,
                                     out_out, ctx_out, alpha_out);
}